// Round 3
// baseline (839.812 us; speedup 1.0000x reference)
//
#include <hip/hip_runtime.h>
#include <hip/hip_bf16.h>

// Problem constants
#define B_     16384
#define TD     512     // T*D
#define HID    128
#define LAT    512     // N_TOKENS*CODE_DIM
#define NCODES 512
#define CDIM   64
#define NTOK   8
#define EPS    1e-5f

// ---------------------------------------------------------------------------
// c2[c] = sum_d codebook[c][d]^2   (one wave per code)
// ---------------------------------------------------------------------------
__global__ void c2_kernel(const float* __restrict__ cb, float* __restrict__ c2) {
    int c = blockIdx.x;
    int d = threadIdx.x;            // 64 threads = 1 wave
    float v = cb[c * CDIM + d];
    float s = v * v;
#pragma unroll
    for (int m = 32; m >= 1; m >>= 1) s += __shfl_xor(s, m, 64);
    if (d == 0) c2[c] = s;
}

// ---------------------------------------------------------------------------
// Row-per-thread GEMM: C[M,N] = A[M,K] @ W[K,N] + bias (+ReLU / +LN-per-64).
// m-tile 256 (1 row/thread), n-tile BN, k-chunk 32.
// A tile staged to LDS TRANSPOSED with stride 257 -> bank (k+tid)%32, 2-way
// aliasing only (free). Per k-chunk each thread does 32 ds_read_b32 then
// BN*32 FMAs -> LDS traffic is negligible; W rows are wave-uniform loads
// (scalar pipe), so the VALU runs v_fmac with an SGPR operand.
// ---------------------------------------------------------------------------
template<int BN, bool RELU, bool LN>
__launch_bounds__(256)
__global__ void gemm_rt(const float* __restrict__ A, const float* __restrict__ W,
                        const float* __restrict__ bias, float* __restrict__ C,
                        int N, int K) {
    constexpr int BK = 32;
    __shared__ float At[BK * 257];          // At[k*257 + r], r=0..255

    const int tid = threadIdx.x;
    const int m0  = blockIdx.x * 256;
    const int row = m0 + tid;
    const int n0  = blockIdx.y * BN;

    float acc[BN];
#pragma unroll
    for (int n = 0; n < BN; ++n) acc[n] = 0.0f;

    for (int k0 = 0; k0 < K; k0 += BK) {
        if (k0) __syncthreads();            // protect At reuse
        // stage A[m0..m0+255][k0..k0+31] transposed; coalesced: 8 lanes/row
#pragma unroll
        for (int p = 0; p < 8; ++p) {
            int idx = p * 256 + tid;        // 0..2047
            int r   = idx >> 3;             // 0..255
            int k4  = (idx & 7) * 4;        // 0,4,..,28
            float4 v = *(const float4*)&A[(size_t)(m0 + r) * K + k0 + k4];
            At[(k4 + 0) * 257 + r] = v.x;
            At[(k4 + 1) * 257 + r] = v.y;
            At[(k4 + 2) * 257 + r] = v.z;
            At[(k4 + 3) * 257 + r] = v.w;
        }
        __syncthreads();

        // own row's k-chunk into registers: bank (k+tid)%32 -> 2-way, free
        float a[BK];
#pragma unroll
        for (int k = 0; k < BK; ++k) a[k] = At[k * 257 + tid];

#pragma unroll
        for (int k = 0; k < BK; ++k) {
            const float* wr = &W[(size_t)(k0 + k) * N + n0];   // wave-uniform
#pragma unroll
            for (int n = 0; n < BN; ++n)
                acc[n] = fmaf(a[k], wr[n], acc[n]);
        }
    }

    // epilogue: bias (+ReLU) (+LN across the BN=64 cols == one token)
#pragma unroll
    for (int n = 0; n < BN; ++n) {
        acc[n] += bias[n0 + n];
        if (RELU) acc[n] = fmaxf(acc[n], 0.0f);
    }
    if (LN) {
        float s = 0.0f, ss = 0.0f;
#pragma unroll
        for (int n = 0; n < BN; ++n) { s += acc[n]; ss = fmaf(acc[n], acc[n], ss); }
        float mean = s * (1.0f / 64.0f);
        float var  = ss * (1.0f / 64.0f) - mean * mean;
        float rstd = rsqrtf(var + EPS);
#pragma unroll
        for (int n = 0; n < BN; ++n) acc[n] = (acc[n] - mean) * rstd;
    }
#pragma unroll
    for (int n = 0; n < BN; n += 4) {
        float4 o = make_float4(acc[n], acc[n + 1], acc[n + 2], acc[n + 3]);
        *(float4*)&C[(size_t)row * N + n0 + n] = o;
    }
}

// ---------------------------------------------------------------------------
// VQ: one thread per token. z (64 floats) in 16 float4 VGPRs; codebook rows
// are wave-uniform -> scalar loads on the scalar pipe, zero LDS. Thread-local
// argmin with ascending-c strict-< == numpy first-min tie-break.
// score = c2[c] - 2*dot(z, cb[c]).
// ---------------------------------------------------------------------------
__launch_bounds__(256)
__global__ void vq_kernel(const float* __restrict__ zln, const float* __restrict__ cb,
                          const float* __restrict__ c2, float* __restrict__ zq_ws,
                          float* __restrict__ zq_out, float* __restrict__ idx_out) {
    const int tok = blockIdx.x * 256 + threadIdx.x;

    float4 z[16];
    const float4* zp = (const float4*)(zln + (size_t)tok * CDIM);
#pragma unroll
    for (int j = 0; j < 16; ++j) z[j] = zp[j];

    const float4* cbv = (const float4*)cb;
    float best = 3.4e38f;
    int   bi   = 0;

    for (int c = 0; c < NCODES; ++c) {
        // 256B of codebook row: wave-uniform -> s_load_dwordx16 x4
        float4 w[16];
#pragma unroll
        for (int j = 0; j < 16; ++j) w[j] = cbv[c * 16 + j];
        // 4 independent FMA chains to break dependency latency
        float a0 = 0.f, a1 = 0.f, a2 = 0.f, a3 = 0.f;
#pragma unroll
        for (int j = 0; j < 16; j += 4) {
            a0 = fmaf(z[j + 0].x, w[j + 0].x, a0);
            a0 = fmaf(z[j + 0].y, w[j + 0].y, a0);
            a0 = fmaf(z[j + 0].z, w[j + 0].z, a0);
            a0 = fmaf(z[j + 0].w, w[j + 0].w, a0);
            a1 = fmaf(z[j + 1].x, w[j + 1].x, a1);
            a1 = fmaf(z[j + 1].y, w[j + 1].y, a1);
            a1 = fmaf(z[j + 1].z, w[j + 1].z, a1);
            a1 = fmaf(z[j + 1].w, w[j + 1].w, a1);
            a2 = fmaf(z[j + 2].x, w[j + 2].x, a2);
            a2 = fmaf(z[j + 2].y, w[j + 2].y, a2);
            a2 = fmaf(z[j + 2].z, w[j + 2].z, a2);
            a2 = fmaf(z[j + 2].w, w[j + 2].w, a2);
            a3 = fmaf(z[j + 3].x, w[j + 3].x, a3);
            a3 = fmaf(z[j + 3].y, w[j + 3].y, a3);
            a3 = fmaf(z[j + 3].z, w[j + 3].z, a3);
            a3 = fmaf(z[j + 3].w, w[j + 3].w, a3);
        }
        float dot = (a0 + a1) + (a2 + a3);
        float s   = fmaf(-2.0f, dot, c2[c]);
        if (s < best) { best = s; bi = c; }   // ascending c, strict <
    }

    // gather codebook[bi] (per-lane divergent; 128KB codebook is L1/L2-hot)
    const float4* q = cbv + (size_t)bi * 16;
    float4* dws = (float4*)(zq_ws  + (size_t)tok * CDIM);
    float4* dout = (float4*)(zq_out + (size_t)tok * CDIM);
#pragma unroll
    for (int j = 0; j < 16; ++j) {
        float4 v = q[j];
        dws[j]  = v;
        dout[j] = v;
    }
    idx_out[tok] = (float)bi;
}

// ---------------------------------------------------------------------------
extern "C" void kernel_launch(void* const* d_in, const int* in_sizes, int n_in,
                              void* d_out, int out_size, void* d_ws, size_t ws_size,
                              hipStream_t stream) {
    const float* x      = (const float*)d_in[0];
    const float* enc_w1 = (const float*)d_in[1];
    const float* enc_b1 = (const float*)d_in[2];
    const float* enc_w2 = (const float*)d_in[3];
    const float* enc_b2 = (const float*)d_in[4];
    const float* cbk    = (const float*)d_in[5];
    const float* dec_w1 = (const float*)d_in[6];
    const float* dec_b1 = (const float*)d_in[7];
    const float* dec_w2 = (const float*)d_in[8];
    const float* dec_b2 = (const float*)d_in[9];

    // outputs, all float32, concatenated flat: recon | z_q | indices
    float* out     = (float*)d_out;
    float* recon_o = out;
    float* zq_o    = out + (size_t)B_ * TD;
    float* idx_o   = out + 2 * (size_t)B_ * TD;

    // workspace: zbuf [B,512] (z_e_ln then z_q), hbuf [B,128], c2[512]
    float* zbuf  = (float*)d_ws;
    float* hbuf  = zbuf + (size_t)B_ * TD;
    float* c2buf = hbuf + (size_t)B_ * HID;

    hipLaunchKernelGGL(c2_kernel, dim3(NCODES), dim3(64), 0, stream, cbk, c2buf);

    // encoder GEMM1 + ReLU: [B,512] @ [512,128] -> hbuf   (grid 64x4 = 256)
    hipLaunchKernelGGL((gemm_rt<32, true, false>), dim3(B_ / 256, HID / 32), dim3(256), 0,
                       stream, x, enc_w1, enc_b1, hbuf, HID, TD);

    // encoder GEMM2 + LN: [B,128] @ [128,512] -> zbuf     (grid 64x8 = 512)
    hipLaunchKernelGGL((gemm_rt<64, false, true>), dim3(B_ / 256, LAT / 64), dim3(256), 0,
                       stream, hbuf, enc_w2, enc_b2, zbuf, LAT, HID);

    // VQ: argmin + gather; zbuf becomes z_q; writes zq/idx fp32 outputs
    hipLaunchKernelGGL(vq_kernel, dim3(B_ * NTOK / 256), dim3(256), 0, stream,
                       zbuf, cbk, c2buf, zbuf, zq_o, idx_o);

    // decoder GEMM1 + ReLU: [B,512] @ [512,128] -> hbuf   (grid 64x4)
    hipLaunchKernelGGL((gemm_rt<32, true, false>), dim3(B_ / 256, HID / 32), dim3(256), 0,
                       stream, zbuf, dec_w1, dec_b1, hbuf, HID, TD);

    // decoder GEMM2: [B,128] @ [128,512] -> recon fp32    (grid 64x8)
    hipLaunchKernelGGL((gemm_rt<64, false, false>), dim3(B_ / 256, TD / 64), dim3(256), 0,
                       stream, hbuf, dec_w2, dec_b2, recon_o, TD, HID);
}

// Round 4
// 376.997 us; speedup vs baseline: 2.2276x; 2.2276x over previous
//
#include <hip/hip_runtime.h>
#include <hip/hip_bf16.h>

// Problem constants
#define B_     16384
#define TD     512     // T*D
#define HID    128
#define LAT    512     // N_TOKENS*CODE_DIM
#define NCODES 512
#define CDIM   64
#define EPS    1e-5f

typedef __attribute__((ext_vector_type(8))) short bf16x8;
typedef __attribute__((ext_vector_type(4))) float f32x4;

// fp32 -> bf16 round-to-nearest-even (bit trick; no NaN inputs here)
static __device__ __forceinline__ unsigned short f2bf(float x) {
    unsigned int u = __float_as_uint(x);
    u = (u + 0x7FFFu + ((u >> 16) & 1u)) >> 16;
    return (unsigned short)u;
}

// ---------------------------------------------------------------------------
// c2[c] = sum_d codebook[c][d]^2   (one wave per code)
// ---------------------------------------------------------------------------
__global__ void c2_kernel(const float* __restrict__ cb, float* __restrict__ c2) {
    int c = blockIdx.x;
    int d = threadIdx.x;            // 64 threads = 1 wave
    float v = cb[c * CDIM + d];
    float s = v * v;
#pragma unroll
    for (int m = 32; m >= 1; m >>= 1) s += __shfl_xor(s, m, 64);
    if (d == 0) c2[c] = s;
}

// ---------------------------------------------------------------------------
// Weight prep for MFMA decoder: w1t[n=128][k=512] = bf16(dec_w1[k][n]),
// w2t[n=512][k=128] = bf16(dec_w2[k][n]).  131072 threads total.
// ---------------------------------------------------------------------------
__global__ void prep_kernel(const float* __restrict__ w1, const float* __restrict__ w2,
                            unsigned short* __restrict__ w1t, unsigned short* __restrict__ w2t) {
    int i = blockIdx.x * 256 + threadIdx.x;      // 0..131071
    if (i < 65536) {
        int n = i >> 9, k = i & 511;             // w1t[n][k]
        w1t[i] = f2bf(w1[k * HID + n]);
    } else {
        int j = i - 65536;
        int n = j >> 7, k = j & 127;             // w2t[n][k]
        w2t[j] = f2bf(w2[k * TD + n]);
    }
}

// ---------------------------------------------------------------------------
// fp32 GEMM (encoder): C[M,N] = A[M,K]@W[K,N] + bias (+ReLU / +LN per 64 cols)
// BM=128, BN=64, BK=32, 256 threads, 8x4 microtile.
// a-reads: As[k][ty*8..] -> 4 distinct addrs x 16-lane broadcast = conflict-free.
// w-reads: Ws[k][tx*4..] -> 2-way bank aliasing = free.
// fmaf chains ascending-k == bit-identical to the round-2 kernel (argmin-safe).
// ---------------------------------------------------------------------------
template<bool RELU, bool LN>
__launch_bounds__(256)
__global__ void gemm_f32(const float* __restrict__ A, const float* __restrict__ W,
                         const float* __restrict__ bias, float* __restrict__ C,
                         int N, int K) {
    __shared__ float As[32 * 132];   // As[k*132 + m], m=0..127
    __shared__ float Ws[32 * 68];    // Ws[k*68 + n],  n=0..63

    const int tid = threadIdx.x;
    const int tx  = tid & 15;        // cols: 4 each
    const int ty  = tid >> 4;        // rows: 8 each
    const int n0  = blockIdx.x * 64;
    const int m0  = blockIdx.y * 128;

    float acc[8][4] = {};

    for (int k0 = 0; k0 < K; k0 += 32) {
        if (k0) __syncthreads();
        // stage A tile transposed (128 rows x 32 k)
#pragma unroll
        for (int p = 0; p < 4; ++p) {
            int idx = p * 256 + tid;           // 0..1023
            int r   = idx >> 3;                // 0..127
            int k4  = (idx & 7) * 4;
            float4 v = *(const float4*)&A[(size_t)(m0 + r) * K + k0 + k4];
            As[(k4 + 0) * 132 + r] = v.x;
            As[(k4 + 1) * 132 + r] = v.y;
            As[(k4 + 2) * 132 + r] = v.z;
            As[(k4 + 3) * 132 + r] = v.w;
        }
        // stage W tile (32 k x 64 n)
#pragma unroll
        for (int p = 0; p < 2; ++p) {
            int idx = p * 256 + tid;           // 0..511
            int k   = idx >> 4;
            int c4  = (idx & 15) * 4;
            *(float4*)&Ws[k * 68 + c4] = *(const float4*)&W[(size_t)(k0 + k) * N + n0 + c4];
        }
        __syncthreads();

#pragma unroll 8
        for (int k = 0; k < 32; ++k) {
            float a0[8], w0[4];
            *(float4*)&a0[0] = *(const float4*)&As[k * 132 + ty * 8];
            *(float4*)&a0[4] = *(const float4*)&As[k * 132 + ty * 8 + 4];
            *(float4*)&w0[0] = *(const float4*)&Ws[k * 68 + tx * 4];
#pragma unroll
            for (int i = 0; i < 8; ++i)
#pragma unroll
                for (int j = 0; j < 4; ++j)
                    acc[i][j] = fmaf(a0[i], w0[j], acc[i][j]);
        }
    }

    float bv[4];
#pragma unroll
    for (int j = 0; j < 4; ++j) bv[j] = bias[n0 + tx * 4 + j];

#pragma unroll
    for (int i = 0; i < 8; ++i) {
        float c[4];
#pragma unroll
        for (int j = 0; j < 4; ++j) {
            c[j] = acc[i][j] + bv[j];
            if (RELU) c[j] = fmaxf(c[j], 0.0f);
        }
        if (LN) {
            float s  = c[0] + c[1] + c[2] + c[3];
            float ss = c[0]*c[0] + c[1]*c[1] + c[2]*c[2] + c[3]*c[3];
#pragma unroll
            for (int m = 1; m <= 8; m <<= 1) {
                s  += __shfl_xor(s,  m, 64);
                ss += __shfl_xor(ss, m, 64);
            }
            float mean = s * (1.0f / 64.0f);
            float var  = ss * (1.0f / 64.0f) - mean * mean;
            float rstd = rsqrtf(var + EPS);
#pragma unroll
            for (int j = 0; j < 4; ++j) c[j] = (c[j] - mean) * rstd;
        }
        *(float4*)&C[(size_t)(m0 + ty * 8 + i) * N + n0 + tx * 4] =
            make_float4(c[0], c[1], c[2], c[3]);
    }
}

// ---------------------------------------------------------------------------
// VQ: 128 tokens x 512 codes per block, 8x8 microtile.
// token-reads broadcast; code-reads 4x ds_read_b64 interleaved (conflict-free).
// Dot chains ascending-k -> bit-identical to round-2 scores -> same indices.
// ---------------------------------------------------------------------------
__launch_bounds__(256)
__global__ void vq_kernel(const float* __restrict__ zln, const float* __restrict__ cb,
                          const float* __restrict__ c2, float* __restrict__ zq_ws,
                          float* __restrict__ zq_out, float* __restrict__ idx_out) {
    __shared__ float Zs[CDIM * 132];     // Zs[d*132 + tok], 128 tokens
    __shared__ float CBs[CDIM * 132];    // CBs[d*132 + c], 128-code chunk
    __shared__ float c2s[NCODES];

    const int tid = threadIdx.x;
    const int tx  = tid & 15;            // codes: 8 each (interleaved)
    const int ty  = tid >> 4;            // tokens: 8 each
    const int m0  = blockIdx.x * 128;

    // stage z tile transposed
#pragma unroll
    for (int p = 0; p < 8; ++p) {
        int idx = p * 256 + tid;         // 0..2047
        int r   = idx >> 4;              // 0..127
        int d4  = (idx & 15) * 4;
        float4 v = *(const float4*)&zln[(size_t)(m0 + r) * CDIM + d4];
        Zs[(d4 + 0) * 132 + r] = v.x;
        Zs[(d4 + 1) * 132 + r] = v.y;
        Zs[(d4 + 2) * 132 + r] = v.z;
        Zs[(d4 + 3) * 132 + r] = v.w;
    }
    c2s[tid]       = c2[tid];
    c2s[tid + 256] = c2[tid + 256];

    float best[8];
    int   bidx[8];
#pragma unroll
    for (int i = 0; i < 8; ++i) { best[i] = 3.4e38f; bidx[i] = 0; }

    for (int c0 = 0; c0 < NCODES; c0 += 128) {
        __syncthreads();   // protect CBs reuse (covers Zs/c2s on first pass)
#pragma unroll
        for (int p = 0; p < 8; ++p) {
            int idx = p * 256 + tid;
            int c   = idx >> 4;
            int d4  = (idx & 15) * 4;
            float4 v = *(const float4*)&cb[(size_t)(c0 + c) * CDIM + d4];
            CBs[(d4 + 0) * 132 + c] = v.x;
            CBs[(d4 + 1) * 132 + c] = v.y;
            CBs[(d4 + 2) * 132 + c] = v.z;
            CBs[(d4 + 3) * 132 + c] = v.w;
        }
        __syncthreads();

        float cr[8][8] = {};
#pragma unroll 4
        for (int k = 0; k < CDIM; ++k) {
            float a0[8], w0[8];
            *(float4*)&a0[0] = *(const float4*)&Zs[k * 132 + ty * 8];       // broadcast
            *(float4*)&a0[4] = *(const float4*)&Zs[k * 132 + ty * 8 + 4];   // broadcast
            *(float2*)&w0[0] = *(const float2*)&CBs[k * 132 + 2 * tx];      // b64, CF
            *(float2*)&w0[2] = *(const float2*)&CBs[k * 132 + 2 * tx + 32];
            *(float2*)&w0[4] = *(const float2*)&CBs[k * 132 + 2 * tx + 64];
            *(float2*)&w0[6] = *(const float2*)&CBs[k * 132 + 2 * tx + 96];
#pragma unroll
            for (int i = 0; i < 8; ++i)
#pragma unroll
                for (int j = 0; j < 8; ++j)
                    cr[i][j] = fmaf(a0[i], w0[j], cr[i][j]);
        }
#pragma unroll
        for (int i = 0; i < 8; ++i)
#pragma unroll
            for (int j = 0; j < 8; ++j) {
                int c   = c0 + 32 * (j >> 1) + 2 * tx + (j & 1);  // ascending in j
                float s = fmaf(-2.0f, cr[i][j], c2s[c]);
                if (s < best[i]) { best[i] = s; bidx[i] = c; }    // strict < = np tie-break
            }
    }

    // reduce over the 16 tx lanes (disjoint code sets), tie-break to lower idx
#pragma unroll
    for (int i = 0; i < 8; ++i) {
        float s = best[i];
        int  bi = bidx[i];
#pragma unroll
        for (int m = 1; m <= 8; m <<= 1) {
            float so = __shfl_xor(s, m, 64);
            int   io = __shfl_xor(bi, m, 64);
            if (so < s || (so == s && io < bi)) { s = so; bi = io; }
        }
        int row = m0 + ty * 8 + i;
        float4 q = *(const float4*)&cb[(size_t)bi * CDIM + tx * 4];
        *(float4*)&zq_ws [(size_t)row * CDIM + tx * 4] = q;
        *(float4*)&zq_out[(size_t)row * CDIM + tx * 4] = q;
        if (tx == 0) idx_out[row] = (float)bi;
    }
}

// ---------------------------------------------------------------------------
// Decoder GEMM1 (MFMA bf16): h2 = relu(z_q @ dec_w1 + b1), output bf16.
// M=16384, K=512, N=128. Wave handles one m16 tile x one n-half (4 n-tiles).
// A (z_q) fp32 -> bf16 in-register. B = w1t[n][k] (pre-transposed bf16).
// ---------------------------------------------------------------------------
__launch_bounds__(256)
__global__ void dec1_mfma(const float* __restrict__ zq, const unsigned short* __restrict__ w1t,
                          const float* __restrict__ b1, unsigned short* __restrict__ h2) {
    const int tid = threadIdx.x;
    const int wv  = tid >> 6;                 // wave 0..3
    const int ln  = tid & 63;
    const int l15 = ln & 15, q = ln >> 4;
    const int mt  = blockIdx.x * 2 + (wv >> 1);   // m16-tile id
    const int nh  = wv & 1;                        // n-half
    const int m   = mt * 16 + l15;

    f32x4 acc[4] = {};

    for (int k0 = 0; k0 < 512; k0 += 32) {
        const float* ap = &zq[(size_t)m * 512 + k0 + q * 8];
        float4 a1 = *(const float4*)ap;
        float4 a2 = *(const float4*)(ap + 4);
        bf16x8 a;
        a[0] = (short)f2bf(a1.x); a[1] = (short)f2bf(a1.y);
        a[2] = (short)f2bf(a1.z); a[3] = (short)f2bf(a1.w);
        a[4] = (short)f2bf(a2.x); a[5] = (short)f2bf(a2.y);
        a[6] = (short)f2bf(a2.z); a[7] = (short)f2bf(a2.w);
#pragma unroll
        for (int t = 0; t < 4; ++t) {
            int n = (nh * 4 + t) * 16 + l15;
            bf16x8 b = *(const bf16x8*)&w1t[(size_t)n * 512 + k0 + q * 8];
            acc[t] = __builtin_amdgcn_mfma_f32_16x16x32_bf16(a, b, acc[t], 0, 0, 0);
        }
    }
#pragma unroll
    for (int t = 0; t < 4; ++t) {
        int col = (nh * 4 + t) * 16 + l15;
        float bb = b1[col];
#pragma unroll
        for (int r = 0; r < 4; ++r) {
            int row = mt * 16 + q * 4 + r;
            float v = fmaxf(acc[t][r] + bb, 0.0f);
            h2[(size_t)row * 128 + col] = f2bf(v);
        }
    }
}

// ---------------------------------------------------------------------------
// Decoder GEMM2 (MFMA bf16): recon = h2 @ dec_w2 + b2, fp32 out.
// M=16384, K=128, N=512. Block = one m16 tile; wave handles 8 n-tiles.
// ---------------------------------------------------------------------------
__launch_bounds__(256)
__global__ void dec2_mfma(const unsigned short* __restrict__ h2, const unsigned short* __restrict__ w2t,
                          const float* __restrict__ b2, float* __restrict__ recon) {
    const int tid = threadIdx.x;
    const int wv  = tid >> 6, ln = tid & 63;
    const int l15 = ln & 15, q = ln >> 4;
    const int mt  = blockIdx.x;
    const int m   = mt * 16 + l15;

    f32x4 acc[8] = {};
#pragma unroll
    for (int k0 = 0; k0 < 128; k0 += 32) {
        bf16x8 a = *(const bf16x8*)&h2[(size_t)m * 128 + k0 + q * 8];
#pragma unroll
        for (int t = 0; t < 8; ++t) {
            int n = (wv * 8 + t) * 16 + l15;
            bf16x8 b = *(const bf16x8*)&w2t[(size_t)n * 128 + k0 + q * 8];
            acc[t] = __builtin_amdgcn_mfma_f32_16x16x32_bf16(a, b, acc[t], 0, 0, 0);
        }
    }
#pragma unroll
    for (int t = 0; t < 8; ++t) {
        int col = (wv * 8 + t) * 16 + l15;
        float bb = b2[col];
#pragma unroll
        for (int r = 0; r < 4; ++r) {
            int row = mt * 16 + q * 4 + r;
            recon[(size_t)row * 512 + col] = acc[t][r] + bb;
        }
    }
}

// ---------------------------------------------------------------------------
extern "C" void kernel_launch(void* const* d_in, const int* in_sizes, int n_in,
                              void* d_out, int out_size, void* d_ws, size_t ws_size,
                              hipStream_t stream) {
    const float* x      = (const float*)d_in[0];
    const float* enc_w1 = (const float*)d_in[1];
    const float* enc_b1 = (const float*)d_in[2];
    const float* enc_w2 = (const float*)d_in[3];
    const float* enc_b2 = (const float*)d_in[4];
    const float* cbk    = (const float*)d_in[5];
    const float* dec_w1 = (const float*)d_in[6];
    const float* dec_b1 = (const float*)d_in[7];
    const float* dec_w2 = (const float*)d_in[8];
    const float* dec_b2 = (const float*)d_in[9];

    // outputs, all float32, concatenated flat: recon | z_q | indices
    float* out     = (float*)d_out;
    float* recon_o = out;
    float* zq_o    = out + (size_t)B_ * TD;
    float* idx_o   = out + 2 * (size_t)B_ * TD;

    // workspace (41.95 MB total, same as round 2):
    //   zbuf [B,512] f32 (z_e_ln then z_q) | hbuf [B,128] f32 | c2 [512] f32
    //   hbuf region reused after enc2: [0,4MB) h2 bf16, [6MB,6.25MB) w1t|w2t bf16
    float* zbuf  = (float*)d_ws;
    float* hbuf  = zbuf + (size_t)B_ * TD;
    float* c2buf = hbuf + (size_t)B_ * HID;
    unsigned short* h2bf = (unsigned short*)hbuf;                       // 4 MB
    unsigned short* w1t  = (unsigned short*)(hbuf + 1572864);           // 128 KB
    unsigned short* w2t  = w1t + 65536;                                 // 128 KB

    hipLaunchKernelGGL(c2_kernel, dim3(NCODES), dim3(64), 0, stream, cbk, c2buf);

    // encoder GEMM1 + ReLU: [B,512]@[512,128] -> hbuf   grid (2,128)
    hipLaunchKernelGGL((gemm_f32<true, false>), dim3(HID / 64, B_ / 128), dim3(256), 0,
                       stream, x, enc_w1, enc_b1, hbuf, HID, TD);

    // encoder GEMM2 + LN: [B,128]@[128,512] -> zbuf     grid (8,128)
    hipLaunchKernelGGL((gemm_f32<false, true>), dim3(LAT / 64, B_ / 128), dim3(256), 0,
                       stream, hbuf, enc_w2, enc_b2, zbuf, LAT, HID);

    // decoder weight prep (after enc2 has consumed hbuf)
    hipLaunchKernelGGL(prep_kernel, dim3(512), dim3(256), 0, stream,
                       dec_w1, dec_w2, w1t, w2t);

    // VQ: 1024 blocks x 128 tokens
    hipLaunchKernelGGL(vq_kernel, dim3(B_ * 8 / 128), dim3(256), 0, stream,
                       zbuf, cbk, c2buf, zbuf, zq_o, idx_o);

    // decoder GEMM1 (MFMA): z_q -> h2 bf16              grid 512
    hipLaunchKernelGGL(dec1_mfma, dim3(512), dim3(256), 0, stream,
                       zbuf, w1t, dec_b1, h2bf);

    // decoder GEMM2 (MFMA): h2 -> recon fp32            grid 1024
    hipLaunchKernelGGL(dec2_mfma, dim3(1024), dim3(256), 0, stream,
                       h2bf, w2t, dec_b2, recon_o);
}